// Round 4
// baseline (54.478 us; speedup 1.0000x reference)
//
#include <hip/hip_runtime.h>
#include <math.h>

#define NUM_CLASSES 80
#define BB 16
#define AA 3
#define HH 85
#define WW 85
#define HW (HH*WW)
#define MM 50
#define CH (AA*(5+NUM_CLASSES))   // 255
#define BX ((HW + 255)/256)       // 29 hw-windows
#define NBLK (BX*BB*AA)           // 1392 blocks
#define PB (AA*BX)                // 87 blocks per batch

__device__ __forceinline__ float sigmoidf_(float x){ return 1.0f/(1.0f+expf(-x)); }
// log(1+e^x), stable; bce(sigmoid(x),t) == softplus(x) - t*x  (exact identity, no saturation at |x|<~16)
__device__ __forceinline__ float softplus_(float x){
    return fmaxf(x, 0.0f) + log1pf(expf(-fabsf(x)));
}

__global__ void __launch_bounds__(256) k_all(
        const float* __restrict__ outputs,
        const float* __restrict__ targets,
        const float* __restrict__ masked_anchors,
        const float* __restrict__ ref_anchors,
        const int* __restrict__ anchor_mask,
        double* __restrict__ part_l,
        double* __restrict__ part_lc,
        int*    __restrict__ part_pos,
        unsigned int* __restrict__ cnt,
        float* __restrict__ out)
{
    __shared__ float s_gx1[MM], s_gy1[MM], s_gx2[MM], s_gy2[MM], s_garea[MM];
    __shared__ float s_delta[MM][4];
    __shared__ float s_scale[MM];
    __shared__ int   s_no;
    __shared__ int   s_win[256];
    __shared__ unsigned int s_cm[256][3];
    __shared__ double s_rl[4], s_rlc[4];
    __shared__ int   s_anyw[4];
    __shared__ int   s_prev;
    __shared__ int   s_posb[BB];

    const int tid  = threadIdx.x;
    const int ba   = blockIdx.y;           // b*AA + a
    const int b    = ba / AA, a = ba % AA;
    const int base = blockIdx.x << 8;
    const int bid  = ba * BX + blockIdx.x;

    // Poison/garbage fix for the ticket counter: legitimate mid-call values are
    // in [0, NBLK); anything >= NBLK (0xAAAAAAAA poison) is stale -> CAS to 0.
    // Any block that increments has already run this check, so a successful CAS
    // can only happen before any increment of this call.
    if (tid == 0){
        unsigned int v = __hip_atomic_load(cnt, __ATOMIC_RELAXED, __HIP_MEMORY_SCOPE_AGENT);
        if (v >= (unsigned int)NBLK) atomicCAS(cnt, v, 0u);
    }

    s_win[tid] = -1;
    s_cm[tid][0] = 0u; s_cm[tid][1] = 0u; s_cm[tid][2] = 0u;

    // ---- phase A: per-GT metadata for batch b (threads 0..MM-1, all in wave 0) ----
    float g0=0.f,g1=0.f,g2=0.f,g3=0.f,g4=0.f;
    bool gflag = false;
    if (tid < MM){
        const float* g = targets + ((size_t)b*MM + tid)*5;
        g0=g[0]; g1=g[1]; g2=g[2]; g3=g[3]; g4=g[4];
        gflag = (g0+g1+g2+g3+g4) > 0.0f;
    }
    unsigned long long bal = __ballot(gflag);
    if (tid == 0) s_no = __popcll(bal);
    __syncthreads();
    const int no = s_no;

    if (tid < MM){
        float gx = g0*(float)WW, gy = g1*(float)HH, gw = g2*(float)WW, gh = g3*(float)HH;
        int cls = min(max((int)g4, 0), NUM_CLASSES-1);
        bool valid = (tid < no);
        int cx = (int)floorf(gx), cy = (int)floorf(gy);
        int cell = min(max(cy*WW + cx, 0), HW-1);
        float xg = (float)(cell % WW), yg = (float)(cell / WW);
        float gx1 = gx - gw*0.5f, gy1 = gy - gh*0.5f;
        float gx2 = gx + gw*0.5f, gy2 = gy + gh*0.5f;
        float garea = gw*gh;
        // 9-anchor argmax via cross-multiplication (first-max-wins, like jnp.argmax)
        float bai = -1.0f, bun = 1.0f; int aidx = 0;
        for (int r = 0; r < 9; ++r){
            float off = (r % 3 == 0) ? 0.5f : 0.0f;  // ref_grid.at[:, 0::3, :2].add(0.5)
            float acx = xg + off, acy = yg + off;
            float aw = ref_anchors[2*r], ah = ref_anchors[2*r+1];
            float tlx = fmaxf(acx - aw*0.5f, gx1), tly = fmaxf(acy - ah*0.5f, gy1);
            float brx = fminf(acx + aw*0.5f, gx2), bry = fminf(acy + ah*0.5f, gy2);
            float ai = (tlx < brx && tly < bry) ? (brx - tlx)*(bry - tly) : 0.0f;
            float un = aw*ah + garea - ai;
            if (ai*bun > bai*un){ bai = ai; bun = un; aidx = r; }
        }
        bool dof = valid && (aidx == anchor_mask[0] || aidx == anchor_mask[1] || aidx == anchor_mask[2]);
        int a3 = aidx % 3;
        float mw = masked_anchors[2*a3], mh = masked_anchors[2*a3+1];
        s_gx1[tid] = gx1; s_gy1[tid] = gy1; s_gx2[tid] = gx2; s_gy2[tid] = gy2;
        s_garea[tid] = garea;
        s_delta[tid][0] = gx - xg; s_delta[tid][1] = gy - yg;
        s_delta[tid][2] = gw/mw;   s_delta[tid][3] = gh/mh;
        s_scale[tid] = sqrtf(2.0f - gw*gh/(float)WW/(float)HH);
        if (dof && a3 == a){
            int ci = cell - base;
            if (ci >= 0 && ci < 256){
                atomicMax(&s_win[ci], tid);                       // last-m-wins (scan overwrite)
                atomicOr(&s_cm[ci][cls >> 5], 1u << (cls & 31));  // OR of one-hots
            }
        }
    }
    __syncthreads();

    // ---- phase B: per-cell loss ----
    double l = 0.0, lc = 0.0;
    bool pos = false;
    const int hw = base + tid;
    if (hw < HW && no > 0){
        int xg = hw % WW, yg = hw / WW;
        size_t obase = ((size_t)(b*CH + a*(5+NUM_CLASSES)))*HW + hw;
        float o0 = outputs[obase];
        float o1 = outputs[obase + HW];
        float o2 = outputs[obase + 2*HW];
        float o3 = outputs[obase + 3*HW];
        float o4 = outputs[obase + 4*HW];
        float px = sigmoidf_(o0) + (float)xg;
        float py = sigmoidf_(o1) + (float)yg;
        float e2 = expf(o2), e3 = expf(o3);
        float pw = e2*masked_anchors[2*a], ph = e3*masked_anchors[2*a+1];
        float px1 = px - pw*0.5f, py1 = py - ph*0.5f;
        float px2 = px + pw*0.5f, py2 = py + ph*0.5f;
        float parea = pw*ph;
        // max IoU via cross-multiplication (no division in the loop)
        float bax = 0.0f, bun = 1.0f;
        for (int m = 0; m < no; ++m){
            float tlx = fmaxf(px1, s_gx1[m]), tly = fmaxf(py1, s_gy1[m]);
            float brx = fminf(px2, s_gx2[m]), bry = fminf(py2, s_gy2[m]);
            float ai = (tlx < brx && tly < bry) ? (brx - tlx)*(bry - tly) : 0.0f;
            float un = parea + s_garea[m] - ai;
            if (ai*bun > bax*un){ bax = ai; bun = un; }
        }
        pos = (bax > 0.7f*bun);
        int win = s_win[tid];
        float sp4 = softplus_(o4);
        if (win >= 0){
            float mi = bax/bun;                      // single division, winner cells only
            l += (double)(sp4 - mi*o4);              // bce(sigma(o4), mi)
            float dx = s_delta[win][0], dy = s_delta[win][1];
            float dw = s_delta[win][2], dh = s_delta[win][3];
            float s = s_scale[win];
            float w2 = s*s;
            l += (double)((softplus_(o0) - dx*o0)*w2);
            l += (double)((softplus_(o1) - dy*o1)*w2);
            float d2 = e2*s - dw*s, d3 = e3*s - dh*s;
            l += 0.5*((double)(d2*d2) + (double)(d3*d3));
            unsigned int c0 = s_cm[tid][0], c1 = s_cm[tid][1], c2 = s_cm[tid][2];
            #pragma unroll 8
            for (int c = 0; c < NUM_CLASSES; ++c){
                float oc = outputs[obase + (size_t)(5+c)*HW];
                unsigned int w = (c < 32) ? c0 : ((c < 64) ? c1 : c2);
                float tt = ((w >> (c & 31)) & 1u) ? 1.0f : 0.0f;
                l += (double)(softplus_(oc) - tt*oc);
            }
        } else {
            if (bax >= 0.7f*bun) lc += (double)sp4;  // kept only if npos[b]==0
            else                 l  += (double)sp4;
        }
    }

    // ---- block reduce (shuffle tree, then 4 wave partials) ----
    for (int off = 32; off > 0; off >>= 1){
        l  += __shfl_down(l,  off);
        lc += __shfl_down(lc, off);
    }
    unsigned long long pbal = __ballot(pos);
    int wid = tid >> 6;
    if ((tid & 63) == 0){
        s_rl[wid] = l; s_rlc[wid] = lc; s_anyw[wid] = (pbal != 0ull) ? 1 : 0;
    }
    __syncthreads();
    if (tid == 0){
        part_l[bid]  = s_rl[0] + s_rl[1] + s_rl[2] + s_rl[3];
        part_lc[bid] = s_rlc[0] + s_rlc[1] + s_rlc[2] + s_rlc[3];
        part_pos[bid] = s_anyw[0] | s_anyw[1] | s_anyw[2] | s_anyw[3];
        unsigned int prev = __hip_atomic_fetch_add(cnt, 1u, __ATOMIC_ACQ_REL,
                                                   __HIP_MEMORY_SCOPE_AGENT);
        s_prev = (int)prev;
    }
    __syncthreads();

    // ---- last block: final reduction ----
    if (s_prev == NBLK - 1){
        __threadfence();                 // invalidate caches; partials fresh
        if (tid < BB) s_posb[tid] = 0;
        __syncthreads();
        for (int i = tid; i < NBLK; i += 256){
            if (part_pos[i]) atomicOr(&s_posb[i / PB], 1);
        }
        __syncthreads();
        double sum = 0.0;
        for (int i = tid; i < NBLK; i += 256){
            sum += part_l[i];
            if (!s_posb[i / PB]) sum += part_lc[i];
        }
        for (int off = 32; off > 0; off >>= 1) sum += __shfl_down(sum, off);
        if ((tid & 63) == 0) s_rl[tid >> 6] = sum;
        __syncthreads();
        if (tid == 0){
            out[0] = (float)(s_rl[0] + s_rl[1] + s_rl[2] + s_rl[3]);
            __hip_atomic_store(cnt, 0u, __ATOMIC_RELEASE, __HIP_MEMORY_SCOPE_AGENT);
        }
    }
}

extern "C" void kernel_launch(void* const* d_in, const int* in_sizes, int n_in,
                              void* d_out, int out_size, void* d_ws, size_t ws_size,
                              hipStream_t stream) {
    const float* outputs        = (const float*)d_in[0];
    const float* targets        = (const float*)d_in[1];
    const float* masked_anchors = (const float*)d_in[2];
    const float* ref_anchors    = (const float*)d_in[3];
    const int*   anchor_mask    = (const int*)d_in[4];

    char* ws = (char*)d_ws;
    double* part_l   = (double*)(ws + 0);          // 11136 B
    double* part_lc  = (double*)(ws + 11136);      // 11136 B
    int*    part_pos = (int*)(ws + 22272);         // 5568 B
    unsigned int* cnt = (unsigned int*)(ws + 27840); // 4 B (end 27844)

    dim3 grid(BX, BB*AA);
    k_all<<<grid, 256, 0, stream>>>(outputs, targets, masked_anchors, ref_anchors,
                                    anchor_mask, part_l, part_lc, part_pos, cnt,
                                    (float*)d_out);
}

// Round 5
// 42.308 us; speedup vs baseline: 1.2877x; 1.2877x over previous
//
#include <hip/hip_runtime.h>
#include <math.h>

#define NUM_CLASSES 80
#define BB 16
#define AA 3
#define HH 85
#define WW 85
#define HW (HH*WW)
#define MM 50
#define CH (AA*(5+NUM_CLASSES))   // 255
#define BX ((HW + 255)/256)       // 29 hw-windows
#define NBLK (BX*BB*AA)           // 1392 blocks

__device__ __forceinline__ float sigmoidf_(float x){ return 1.0f/(1.0f+expf(-x)); }
// bce(sigmoid(x),t) == softplus(x) - t*x (exact; no saturation for |x| < ~16)
__device__ __forceinline__ float softplus_(float x){
    return fmaxf(x, 0.0f) + log1pf(expf(-fabsf(x)));
}
__device__ __forceinline__ double atomicExchD(double* p, double v){
    unsigned long long old = atomicExch((unsigned long long*)p, __double_as_longlong(v));
    return __longlong_as_double(old);
}

// ws layout: every slot on its own 128B line; ALL cross-block traffic is relaxed
// device-scope RMWs (coherence-point execution, no cache-maintenance ops).
__global__ void __launch_bounds__(256) k_all(
        const float* __restrict__ outputs,
        const float* __restrict__ targets,
        const float* __restrict__ masked_anchors,
        const float* __restrict__ ref_anchors,
        const int* __restrict__ anchor_mask,
        char* __restrict__ wsb,
        float* __restrict__ out)
{
    double* acc_l  = (double*)(wsb);             // 16 stripes, stride 16 doubles
    double* acc_lc = (double*)(wsb + 2048);      // 16 per-batch, stride 16 doubles
    int*    posfl  = (int*)(wsb + 4096);         // 16 per-batch, stride 32 ints
    unsigned int* cnt = (unsigned int*)(wsb + 6144);

    __shared__ float s_gx1[MM], s_gy1[MM], s_gx2[MM], s_gy2[MM], s_garea[MM];
    __shared__ float s_delta[MM][4];
    __shared__ float s_scale[MM];
    __shared__ int   s_no;
    __shared__ int   s_win[256];
    __shared__ unsigned int s_cm[256][3];
    __shared__ double s_rl[4], s_rlc[4];
    __shared__ int   s_anyw[4];
    __shared__ int   s_prev;
    __shared__ double s_fa[16], s_fc[16];
    __shared__ int   s_fp[16];

    const int tid  = threadIdx.x;
    const int ba   = blockIdx.y;           // b*AA + a
    const int b    = ba / AA, a = ba % AA;
    const int base = blockIdx.x << 8;
    const int bid  = ba * BX + blockIdx.x;

    // Poison fix: cnt==0xAAAAAAAA (harness poison) -> 0. Legit values < NBLK=1392,
    // so this CAS can never fire on live state.
    if (tid == 0) atomicCAS(cnt, 0xAAAAAAAAu, 0u);

    s_win[tid] = -1;
    s_cm[tid][0] = 0u; s_cm[tid][1] = 0u; s_cm[tid][2] = 0u;

    // ---- phase A: per-GT metadata for batch b (threads 0..MM-1, wave 0) ----
    float g0=0.f,g1=0.f,g2=0.f,g3=0.f,g4=0.f;
    bool gflag = false;
    if (tid < MM){
        const float* g = targets + ((size_t)b*MM + tid)*5;
        g0=g[0]; g1=g[1]; g2=g[2]; g3=g[3]; g4=g[4];
        gflag = (g0+g1+g2+g3+g4) > 0.0f;
    }
    unsigned long long bal = __ballot(gflag);
    if (tid == 0) s_no = __popcll(bal);
    __syncthreads();
    const int no = s_no;

    if (tid < MM){
        float gx = g0*(float)WW, gy = g1*(float)HH, gw = g2*(float)WW, gh = g3*(float)HH;
        int cls = min(max((int)g4, 0), NUM_CLASSES-1);
        bool valid = (tid < no);
        int cx = (int)floorf(gx), cy = (int)floorf(gy);
        int cell = min(max(cy*WW + cx, 0), HW-1);
        float xg = (float)(cell % WW), yg = (float)(cell / WW);
        float gx1 = gx - gw*0.5f, gy1 = gy - gh*0.5f;
        float gx2 = gx + gw*0.5f, gy2 = gy + gh*0.5f;
        float garea = gw*gh;
        // 9-anchor argmax via cross-multiplication (first-max-wins, like jnp.argmax)
        float bai = -1.0f, bun = 1.0f; int aidx = 0;
        for (int r = 0; r < 9; ++r){
            float off = (r % 3 == 0) ? 0.5f : 0.0f;  // ref_grid.at[:, 0::3, :2].add(0.5)
            float acx = xg + off, acy = yg + off;
            float aw = ref_anchors[2*r], ah = ref_anchors[2*r+1];
            float tlx = fmaxf(acx - aw*0.5f, gx1), tly = fmaxf(acy - ah*0.5f, gy1);
            float brx = fminf(acx + aw*0.5f, gx2), bry = fminf(acy + ah*0.5f, gy2);
            float ai = (tlx < brx && tly < bry) ? (brx - tlx)*(bry - tly) : 0.0f;
            float un = aw*ah + garea - ai;
            if (ai*bun > bai*un){ bai = ai; bun = un; aidx = r; }
        }
        bool dof = valid && (aidx == anchor_mask[0] || aidx == anchor_mask[1] || aidx == anchor_mask[2]);
        int a3 = aidx % 3;
        float mw = masked_anchors[2*a3], mh = masked_anchors[2*a3+1];
        s_gx1[tid] = gx1; s_gy1[tid] = gy1; s_gx2[tid] = gx2; s_gy2[tid] = gy2;
        s_garea[tid] = garea;
        s_delta[tid][0] = gx - xg; s_delta[tid][1] = gy - yg;
        s_delta[tid][2] = gw/mw;   s_delta[tid][3] = gh/mh;
        s_scale[tid] = sqrtf(2.0f - gw*gh/(float)WW/(float)HH);
        if (dof && a3 == a){
            int ci = cell - base;
            if (ci >= 0 && ci < 256){
                atomicMax(&s_win[ci], tid);                       // last-m-wins (scan overwrite)
                atomicOr(&s_cm[ci][cls >> 5], 1u << (cls & 31));  // OR of one-hots
            }
        }
    }
    __syncthreads();

    // ---- phase B: per-cell loss ----
    double l = 0.0, lc = 0.0;
    bool pos = false;
    const int hw = base + tid;
    if (hw < HW && no > 0){
        int xg = hw % WW, yg = hw / WW;
        size_t obase = ((size_t)(b*CH + a*(5+NUM_CLASSES)))*HW + hw;
        float o0 = outputs[obase];
        float o1 = outputs[obase + HW];
        float o2 = outputs[obase + 2*HW];
        float o3 = outputs[obase + 3*HW];
        float o4 = outputs[obase + 4*HW];
        float px = sigmoidf_(o0) + (float)xg;
        float py = sigmoidf_(o1) + (float)yg;
        float e2 = expf(o2), e3 = expf(o3);
        float pw = e2*masked_anchors[2*a], ph = e3*masked_anchors[2*a+1];
        float px1 = px - pw*0.5f, py1 = py - ph*0.5f;
        float px2 = px + pw*0.5f, py2 = py + ph*0.5f;
        float parea = pw*ph;
        float bax = 0.0f, bun = 1.0f;     // max IoU via cross-multiplication (no fdiv)
        for (int m = 0; m < no; ++m){
            float tlx = fmaxf(px1, s_gx1[m]), tly = fmaxf(py1, s_gy1[m]);
            float brx = fminf(px2, s_gx2[m]), bry = fminf(py2, s_gy2[m]);
            float ai = (tlx < brx && tly < bry) ? (brx - tlx)*(bry - tly) : 0.0f;
            float un = parea + s_garea[m] - ai;
            if (ai*bun > bax*un){ bax = ai; bun = un; }
        }
        pos = (bax > 0.7f*bun);
        int win = s_win[tid];
        float sp4 = softplus_(o4);
        if (win >= 0){
            float mi = bax/bun;                      // one fdiv, winner cells only
            l += (double)(sp4 - mi*o4);              // bce(sigma(o4), mi)
            float dx = s_delta[win][0], dy = s_delta[win][1];
            float dw = s_delta[win][2], dh = s_delta[win][3];
            float s = s_scale[win];
            float w2 = s*s;
            l += (double)((softplus_(o0) - dx*o0)*w2);
            l += (double)((softplus_(o1) - dy*o1)*w2);
            float d2 = e2*s - dw*s, d3 = e3*s - dh*s;
            l += 0.5*((double)(d2*d2) + (double)(d3*d3));
            unsigned int c0 = s_cm[tid][0], c1 = s_cm[tid][1], c2 = s_cm[tid][2];
            #pragma unroll 8
            for (int c = 0; c < NUM_CLASSES; ++c){
                float oc = outputs[obase + (size_t)(5+c)*HW];
                unsigned int w = (c < 32) ? c0 : ((c < 64) ? c1 : c2);
                float tt = ((w >> (c & 31)) & 1u) ? 1.0f : 0.0f;
                l += (double)(softplus_(oc) - tt*oc);
            }
        } else {
            if (bax >= 0.7f*bun) lc += (double)sp4;  // kept only if npos[b]==0
            else                 l  += (double)sp4;
        }
    }

    // ---- block reduce (shuffle tree, 4 wave partials) ----
    for (int off = 32; off > 0; off >>= 1){
        l  += __shfl_down(l,  off);
        lc += __shfl_down(lc, off);
    }
    unsigned long long pbal = __ballot(pos);
    int wid = tid >> 6;
    if ((tid & 63) == 0){
        s_rl[wid] = l; s_rlc[wid] = lc; s_anyw[wid] = (pbal != 0ull) ? 1 : 0;
    }
    __syncthreads();
    if (tid == 0){
        double bl  = s_rl[0] + s_rl[1] + s_rl[2] + s_rl[3];
        double blc = s_rlc[0] + s_rlc[1] + s_rlc[2] + s_rlc[3];
        int anyp = s_anyw[0] | s_anyw[1] | s_anyw[2] | s_anyw[3];
        // relaxed device-scope RMWs: execute at coherence point, NO cache flushes
        atomicAdd(&acc_l[(bid & 15)*16], bl);
        if (blc != 0.0) atomicAdd(&acc_lc[b*16], blc);
        if (anyp) atomicOr(&posfl[b*32], 1);
        __builtin_amdgcn_s_waitcnt(0);   // data RMWs committed before ticket
        s_prev = (int)atomicAdd(cnt, 1u);
    }
    __syncthreads();

    // ---- last block: read+reset every slot with one exchange each ----
    if (s_prev == NBLK - 1){
        if (tid < 16)      s_fa[tid]      = atomicExchD(&acc_l[tid*16], 0.0);
        else if (tid < 32) s_fc[tid - 16] = atomicExchD(&acc_lc[(tid-16)*16], 0.0);
        else if (tid < 48) s_fp[tid - 32] = atomicExch(&posfl[(tid-32)*32], 0);
        __syncthreads();
        if (tid == 0){
            double t = 0.0;
            for (int i = 0; i < 16; ++i) t += s_fa[i];
            for (int bb = 0; bb < BB; ++bb) if (!s_fp[bb]) t += s_fc[bb];
            out[0] = (float)t;
            atomicExch(cnt, 0u);         // self-clean for the next call
        }
    }
}

extern "C" void kernel_launch(void* const* d_in, const int* in_sizes, int n_in,
                              void* d_out, int out_size, void* d_ws, size_t ws_size,
                              hipStream_t stream) {
    const float* outputs        = (const float*)d_in[0];
    const float* targets        = (const float*)d_in[1];
    const float* masked_anchors = (const float*)d_in[2];
    const float* ref_anchors    = (const float*)d_in[3];
    const int*   anchor_mask    = (const int*)d_in[4];

    dim3 grid(BX, BB*AA);
    k_all<<<grid, 256, 0, stream>>>(outputs, targets, masked_anchors, ref_anchors,
                                    anchor_mask, (char*)d_ws, (float*)d_out);
}

// Round 6
// 21.087 us; speedup vs baseline: 2.5835x; 2.0063x over previous
//
#include <hip/hip_runtime.h>
#include <math.h>

#define NUM_CLASSES 80
#define BB 16
#define AA 3
#define HH 85
#define WW 85
#define HW (HH*WW)
#define MM 50
#define CH (AA*(5+NUM_CLASSES))   // 255
#define BX ((HW + 255)/256)       // 29 hw-windows per (b,a)
#define NBA (BB*AA)               // 48 columns
#define NBLK (BX*NBA)             // 1392 blocks

__device__ __forceinline__ float sigmoidf_(float x){ return 1.0f/(1.0f+expf(-x)); }
// bce(sigmoid(x),t) == softplus(x) - t*x (exact; no saturation for |x| < ~16)
__device__ __forceinline__ float softplus_(float x){
    return fmaxf(x, 0.0f) + log1pf(expf(-fabsf(x)));
}
__device__ __forceinline__ double atomicExchD(double* p, double v){
    unsigned long long old = atomicExch((unsigned long long*)p, __double_as_longlong(v));
    return __longlong_as_double(old);
}

// ws layout (128B-line separated):
//   acc_l [16 lines]  @ 0      : striped f64 loss partials (relaxed atomicAdd)
//   acc_lc[16 lines]  @ 2048   : per-batch conditional-conf partials
//   posfl [16 lines]  @ 4096   : per-batch any-positive flags
//   colcnt[48 lines]  @ 6144   : per-ba column tickets (29 blocks each)
//   cnt   [1]         @ 12288  : global ticket (48 column-winners only)
__global__ void __launch_bounds__(256) k_all(
        const float* __restrict__ outputs,
        const float* __restrict__ targets,
        const float* __restrict__ masked_anchors,
        const float* __restrict__ ref_anchors,
        const int* __restrict__ anchor_mask,
        char* __restrict__ wsb,
        float* __restrict__ out)
{
    double* acc_l  = (double*)(wsb);
    double* acc_lc = (double*)(wsb + 2048);
    int*    posfl  = (int*)(wsb + 4096);
    unsigned int* colcnt = (unsigned int*)(wsb + 6144);
    unsigned int* cnt    = (unsigned int*)(wsb + 12288);

    __shared__ float s_gx1[MM], s_gy1[MM], s_gx2[MM], s_gy2[MM], s_garea[MM];
    __shared__ float s_delta[MM][4];
    __shared__ float s_scale[MM];
    __shared__ int   s_no;
    __shared__ int   s_win[256];
    __shared__ unsigned int s_cm[256][3];
    __shared__ double s_rl[4], s_rlc[4];
    __shared__ int   s_anyw[4];
    __shared__ int   s_prev;
    __shared__ double s_fa[16], s_fc[16];
    __shared__ int   s_fp[16];

    const int tid  = threadIdx.x;
    const int ba   = blockIdx.y;           // b*AA + a  (column id)
    const int b    = ba / AA, a = ba % AA;
    const int base = blockIdx.x << 8;
    const int bid  = ba * BX + blockIdx.x;

    // Clean poisoned column ticket. Live values are 0..28 at check time (this
    // block hasn't incremented yet), so a CAS on v>=29 can never hit live state.
    if (tid == 0){
        unsigned int v = __hip_atomic_load(&colcnt[ba*32], __ATOMIC_RELAXED,
                                           __HIP_MEMORY_SCOPE_AGENT);
        if (v >= (unsigned int)BX) atomicCAS(&colcnt[ba*32], v, 0u);
    }

    s_win[tid] = -1;
    s_cm[tid][0] = 0u; s_cm[tid][1] = 0u; s_cm[tid][2] = 0u;

    // ---- phase A: per-GT metadata for batch b (threads 0..MM-1, wave 0) ----
    float g0=0.f,g1=0.f,g2=0.f,g3=0.f,g4=0.f;
    bool gflag = false;
    if (tid < MM){
        const float* g = targets + ((size_t)b*MM + tid)*5;
        g0=g[0]; g1=g[1]; g2=g[2]; g3=g[3]; g4=g[4];
        gflag = (g0+g1+g2+g3+g4) > 0.0f;
    }
    unsigned long long bal = __ballot(gflag);
    if (tid == 0) s_no = __popcll(bal);
    __syncthreads();
    const int no = s_no;

    if (tid < MM){
        float gx = g0*(float)WW, gy = g1*(float)HH, gw = g2*(float)WW, gh = g3*(float)HH;
        int cls = min(max((int)g4, 0), NUM_CLASSES-1);
        bool valid = (tid < no);
        int cx = (int)floorf(gx), cy = (int)floorf(gy);
        int cell = min(max(cy*WW + cx, 0), HW-1);
        float xg = (float)(cell % WW), yg = (float)(cell / WW);
        float gx1 = gx - gw*0.5f, gy1 = gy - gh*0.5f;
        float gx2 = gx + gw*0.5f, gy2 = gy + gh*0.5f;
        float garea = gw*gh;
        // 9-anchor argmax via cross-multiplication (first-max-wins, like jnp.argmax)
        float bai = -1.0f, bun = 1.0f; int aidx = 0;
        for (int r = 0; r < 9; ++r){
            float off = (r % 3 == 0) ? 0.5f : 0.0f;  // ref_grid.at[:, 0::3, :2].add(0.5)
            float acx = xg + off, acy = yg + off;
            float aw = ref_anchors[2*r], ah = ref_anchors[2*r+1];
            float tlx = fmaxf(acx - aw*0.5f, gx1), tly = fmaxf(acy - ah*0.5f, gy1);
            float brx = fminf(acx + aw*0.5f, gx2), bry = fminf(acy + ah*0.5f, gy2);
            float ai = (tlx < brx && tly < bry) ? (brx - tlx)*(bry - tly) : 0.0f;
            float un = aw*ah + garea - ai;
            if (ai*bun > bai*un){ bai = ai; bun = un; aidx = r; }
        }
        bool dof = valid && (aidx == anchor_mask[0] || aidx == anchor_mask[1] || aidx == anchor_mask[2]);
        int a3 = aidx % 3;
        float mw = masked_anchors[2*a3], mh = masked_anchors[2*a3+1];
        s_gx1[tid] = gx1; s_gy1[tid] = gy1; s_gx2[tid] = gx2; s_gy2[tid] = gy2;
        s_garea[tid] = garea;
        s_delta[tid][0] = gx - xg; s_delta[tid][1] = gy - yg;
        s_delta[tid][2] = gw/mw;   s_delta[tid][3] = gh/mh;
        s_scale[tid] = sqrtf(2.0f - gw*gh/(float)WW/(float)HH);
        if (dof && a3 == a){
            int ci = cell - base;
            if (ci >= 0 && ci < 256){
                atomicMax(&s_win[ci], tid);                       // last-m-wins (scan overwrite)
                atomicOr(&s_cm[ci][cls >> 5], 1u << (cls & 31));  // OR of one-hots
            }
        }
    }
    __syncthreads();

    // ---- phase B: per-cell loss ----
    double l = 0.0, lc = 0.0;
    bool pos = false;
    const int hw = base + tid;
    if (hw < HW && no > 0){
        int xg = hw % WW, yg = hw / WW;
        size_t obase = ((size_t)(b*CH + a*(5+NUM_CLASSES)))*HW + hw;
        float o0 = outputs[obase];
        float o1 = outputs[obase + HW];
        float o2 = outputs[obase + 2*HW];
        float o3 = outputs[obase + 3*HW];
        float o4 = outputs[obase + 4*HW];
        float px = sigmoidf_(o0) + (float)xg;
        float py = sigmoidf_(o1) + (float)yg;
        float e2 = expf(o2), e3 = expf(o3);
        float pw = e2*masked_anchors[2*a], ph = e3*masked_anchors[2*a+1];
        float px1 = px - pw*0.5f, py1 = py - ph*0.5f;
        float px2 = px + pw*0.5f, py2 = py + ph*0.5f;
        float parea = pw*ph;
        float bax = 0.0f, bun = 1.0f;     // max IoU via cross-multiplication (no fdiv)
        for (int m = 0; m < no; ++m){
            float tlx = fmaxf(px1, s_gx1[m]), tly = fmaxf(py1, s_gy1[m]);
            float brx = fminf(px2, s_gx2[m]), bry = fminf(py2, s_gy2[m]);
            float ai = (tlx < brx && tly < bry) ? (brx - tlx)*(bry - tly) : 0.0f;
            float un = parea + s_garea[m] - ai;
            if (ai*bun > bax*un){ bax = ai; bun = un; }
        }
        pos = (bax > 0.7f*bun);
        int win = s_win[tid];
        float sp4 = softplus_(o4);
        if (win >= 0){
            float mi = bax/bun;                      // one fdiv, winner cells only
            l += (double)(sp4 - mi*o4);              // bce(sigma(o4), mi)
            float dx = s_delta[win][0], dy = s_delta[win][1];
            float dw = s_delta[win][2], dh = s_delta[win][3];
            float s = s_scale[win];
            float w2 = s*s;
            l += (double)((softplus_(o0) - dx*o0)*w2);
            l += (double)((softplus_(o1) - dy*o1)*w2);
            float d2 = e2*s - dw*s, d3 = e3*s - dh*s;
            l += 0.5*((double)(d2*d2) + (double)(d3*d3));
            unsigned int c0 = s_cm[tid][0], c1 = s_cm[tid][1], c2 = s_cm[tid][2];
            #pragma unroll 8
            for (int c = 0; c < NUM_CLASSES; ++c){
                float oc = outputs[obase + (size_t)(5+c)*HW];
                unsigned int w = (c < 32) ? c0 : ((c < 64) ? c1 : c2);
                float tt = ((w >> (c & 31)) & 1u) ? 1.0f : 0.0f;
                l += (double)(softplus_(oc) - tt*oc);
            }
        } else {
            if (bax >= 0.7f*bun) lc += (double)sp4;  // kept only if npos[b]==0
            else                 l  += (double)sp4;
        }
    }

    // ---- block reduce (shuffle tree, 4 wave partials) ----
    for (int off = 32; off > 0; off >>= 1){
        l  += __shfl_down(l,  off);
        lc += __shfl_down(lc, off);
    }
    unsigned long long pbal = __ballot(pos);
    int wid = tid >> 6;
    if ((tid & 63) == 0){
        s_rl[wid] = l; s_rlc[wid] = lc; s_anyw[wid] = (pbal != 0ull) ? 1 : 0;
    }
    __syncthreads();
    if (tid == 0){
        double bl  = s_rl[0] + s_rl[1] + s_rl[2] + s_rl[3];
        double blc = s_rlc[0] + s_rlc[1] + s_rlc[2] + s_rlc[3];
        int anyp = s_anyw[0] | s_anyw[1] | s_anyw[2] | s_anyw[3];
        // relaxed device-scope RMWs, striped across lines -> no hot-line queue
        atomicAdd(&acc_l[(bid & 15)*16], bl);
        if (blc != 0.0) atomicAdd(&acc_lc[b*16], blc);
        if (anyp) atomicOr(&posfl[b*32], 1);
        __builtin_amdgcn_s_waitcnt(0);   // data RMWs ack'd at coherence point
        int prev = -1;
        unsigned int cp = atomicAdd(&colcnt[ba*32], 1u);
        if (cp == (unsigned int)(BX - 1)){
            // column complete -> global ticket (only 48 blocks ever touch cnt)
            unsigned int v = __hip_atomic_load(cnt, __ATOMIC_RELAXED,
                                              __HIP_MEMORY_SCOPE_AGENT);
            if (v >= (unsigned int)NBA) atomicCAS(cnt, v, 0u);   // poison clean
            prev = (int)atomicAdd(cnt, 1u);
        }
        s_prev = prev;
    }
    __syncthreads();

    // ---- final block (last column-winner): reduce + self-clean all state ----
    if (s_prev == NBA - 1){
        if (tid < 16)      s_fa[tid]      = atomicExchD(&acc_l[tid*16], 0.0);
        else if (tid < 32) s_fc[tid - 16] = atomicExchD(&acc_lc[(tid-16)*16], 0.0);
        else if (tid < 48) s_fp[tid - 32] = atomicExch(&posfl[(tid-32)*32], 0);
        else if (tid < 96) atomicExch(&colcnt[(tid-48)*32], 0u);
        __syncthreads();
        if (tid == 0){
            double t = 0.0;
            for (int i = 0; i < 16; ++i) t += s_fa[i];
            for (int bb = 0; bb < BB; ++bb) if (!s_fp[bb]) t += s_fc[bb];
            out[0] = (float)t;
            atomicExch(cnt, 0u);         // global ticket clean for next call
        }
    }
}

extern "C" void kernel_launch(void* const* d_in, const int* in_sizes, int n_in,
                              void* d_out, int out_size, void* d_ws, size_t ws_size,
                              hipStream_t stream) {
    const float* outputs        = (const float*)d_in[0];
    const float* targets        = (const float*)d_in[1];
    const float* masked_anchors = (const float*)d_in[2];
    const float* ref_anchors    = (const float*)d_in[3];
    const int*   anchor_mask    = (const int*)d_in[4];

    dim3 grid(BX, NBA);
    k_all<<<grid, 256, 0, stream>>>(outputs, targets, masked_anchors, ref_anchors,
                                    anchor_mask, (char*)d_ws, (float*)d_out);
}